// Round 2
// baseline (1429.879 us; speedup 1.0000x reference)
//
#include <hip/hip_runtime.h>

// NCA with hypernetwork, MI355X bf16-MFMA implementation (round 2).
//
// Layouts (all in d_ws, rebuilt every call since ws is poisoned):
//   grid0/grid1/u : bf16, channels-last [s][y][x][ci], per-(y,x) 128B "ci-line",
//                   byte-swizzled  byte ^= ((x&7)<<4)   (bank-conflict-free ds_read_b128)
//   Wbuf          : bf16, [s][conv][tap][co][ci], per-co 128B ci-line,
//                   byte-swizzled  byte ^= ((co&7)<<4)
// Pre-swizzled global layout => global_load_lds stages linear copies (G21).
//
// Round-2 changes:
//   * wgen: 1152 blocks, 1 col x 8 samples per thread (acc[8], no spill) — was
//     144 blocks with 64 spilled accs, 110us latency-bound.
//   * conv: 256 blocks x 512 thr (8 rows/block), stage rows + ALL 9 tap weight
//     tiles (152KB LDS) once, single barrier, barrier-free tap loop.

typedef __attribute__((ext_vector_type(8))) short short8;     // 8 bf16 = 4 VGPR (MFMA frag)
typedef __attribute__((ext_vector_type(4))) float f32x4;      // MFMA acc frag
typedef __attribute__((ext_vector_type(8))) unsigned short us8;

__device__ __forceinline__ unsigned short f2bf(float f) {     // RNE f32->bf16
  unsigned int u = __builtin_bit_cast(unsigned int, f);
  u = (u + 0x7FFFu + ((u >> 16) & 1u)) >> 16;
  return (unsigned short)u;
}
__device__ __forceinline__ float bf2f(unsigned short h) {
  unsigned int u = ((unsigned int)h) << 16;
  return __builtin_bit_cast(float, u);
}

__device__ __forceinline__ void gl_lds16(const void* g, void* l) {
  // 16B-wide async global->LDS; LDS dest is wave-uniform base + lane*16 (m104).
  __builtin_amdgcn_global_load_lds((const __attribute__((address_space(1))) void*)g,
                                   (__attribute__((address_space(3))) void*)l, 16, 0, 0);
}

// ---------------- hypernet trunk: cond -> h1 -> h2 (store h2 transposed [k][s]) --------
__global__ void hyper_kernel(const int* __restrict__ labels, const float* __restrict__ emb,
                             const float* __restrict__ hw1, const float* __restrict__ hb1,
                             const float* __restrict__ hw2, const float* __restrict__ hb2,
                             float* __restrict__ h2T) {
  __shared__ float cond[128];
  __shared__ float h1[256];
  const int s = blockIdx.x, j = threadIdx.x;        // 32 blocks x 256 threads
  if (j < 128) cond[j] = emb[(size_t)labels[s] * 128 + j];
  __syncthreads();
  float a = hb1[j];
  for (int k = 0; k < 128; ++k) a += cond[k] * hw1[k * 256 + j];
  h1[j] = fmaxf(a, 0.f);
  __syncthreads();
  float a2 = hb2[j];
  for (int k = 0; k < 256; ++k) a2 += h1[k] * hw2[k * 256 + j];
  h2T[j * 32 + s] = fmaxf(a2, 0.f);                 // [256][32]
}

// ---------------- FiLM params: film[4][32][64] = g1,be1,g2,be2 -------------------------
__global__ void film_kernel(const int* __restrict__ labels, const float* __restrict__ emb,
                            const float* __restrict__ f1w1, const float* __restrict__ f1b1,
                            const float* __restrict__ f1w2, const float* __restrict__ f1b2,
                            const float* __restrict__ f2w1, const float* __restrict__ f2b1,
                            const float* __restrict__ f2w2, const float* __restrict__ f2b2,
                            float* __restrict__ film) {
  __shared__ float cond[128];
  __shared__ float hid[128];
  const int s = blockIdx.x, which = blockIdx.y, j = threadIdx.x;   // (32,2) x 128
  const float* W1 = which ? f2w1 : f1w1;
  const float* B1 = which ? f2b1 : f1b1;
  const float* W2 = which ? f2w2 : f1w2;
  const float* B2 = which ? f2b2 : f1b2;
  cond[j] = emb[(size_t)labels[s] * 128 + j];
  __syncthreads();
  float a = B1[j];
  for (int k = 0; k < 128; ++k) a += cond[k] * W1[k * 128 + j];
  hid[j] = fmaxf(a, 0.f);
  __syncthreads();
  float p = B2[j];
  for (int k = 0; k < 128; ++k) p += hid[k] * W2[k * 128 + j];
  film[(size_t)((which * 2 + (j >> 6)) * 32 + s) * 64 + (j & 63)] = p;
}

// ---------------- weight generation: h2 @ hw3 + hb3, scatter to swizzled bf16 ----------
// 1152 blocks x 256 threads. Thread = one output column j x 8 samples.
// All 4 waves of a block read the same hw3 lines (L1-served), no redundancy at L2.
__launch_bounds__(256)
__global__ void wgen_kernel(const float* __restrict__ h2T, const float* __restrict__ hw3,
                            const float* __restrict__ hb3, unsigned short* __restrict__ W) {
  __shared__ float h2l[8192];                       // [k=256][s=32]
  const int t = threadIdx.x;
  for (int i = t; i < 8192; i += 256) h2l[i] = h2T[i];
  __syncthreads();
  const int j  = blockIdx.x * 64 + (t & 63);
  const int sg = t >> 6;                            // wave id = sample group (8 samples)
  float acc[8];
  #pragma unroll
  for (int i = 0; i < 8; ++i) acc[i] = 0.f;
  const float* hp = &h2l[sg * 8];
  #pragma unroll 4
  for (int k = 0; k < 256; ++k) {
    const float w = hw3[(size_t)k * 73728 + j];     // 256B/wave coalesced
    const float4 hA = *(const float4*)(hp + k * 32);      // broadcast (uniform addr)
    const float4 hB = *(const float4*)(hp + k * 32 + 4);
    acc[0] += hA.x * w; acc[1] += hA.y * w; acc[2] += hA.z * w; acc[3] += hA.w * w;
    acc[4] += hB.x * w; acc[5] += hB.y * w; acc[6] += hB.z * w; acc[7] += hB.w * w;
  }
  const float bias = hb3[j];
  const int cv = j / 36864;               // which conv
  const int r  = j - cv * 36864;
  const int co = r / 576;
  const int r2 = r - co * 576;
  const int ci = r2 / 9;
  const int tap = r2 - ci * 9;            // ky*3+kx
  const int sw = (co * 64 + ci) ^ ((co & 7) << 3);   // ushort-unit swizzle (byte<<4)
  #pragma unroll
  for (int i = 0; i < 8; ++i) {
    const int s2 = sg * 8 + i;
    W[(size_t)((s2 * 2 + cv) * 9 + tap) * 4096 + sw] = f2bf(acc[i] + bias);
  }
}

// ---------------- initial grid: [B,C,H,W] f32 -> swizzled channels-last bf16 -----------
__global__ void init_kernel(const float* __restrict__ gin, unsigned short* __restrict__ g0) {
  __shared__ float lds[64][65];                     // +1 pad
  const int b = blockIdx.x >> 6, y = blockIdx.x & 63;   // 2048 blocks x 256 threads
  const int t = threadIdx.x;
  {
    const int ci = t >> 2, xq = t & 3;
    const float* base = gin + (size_t)((b * 64 + ci) * 64 + y) * 64;
    #pragma unroll
    for (int q = 0; q < 4; ++q) {
      const int x0 = (xq + q * 4) * 4;
      const float4 v = *(const float4*)(base + x0);
      lds[ci][x0+0] = v.x; lds[ci][x0+1] = v.y; lds[ci][x0+2] = v.z; lds[ci][x0+3] = v.w;
    }
  }
  __syncthreads();
  const int x = t >> 2, cq = t & 3, ci0 = cq * 16;
  us8 lo, hi;
  #pragma unroll
  for (int i = 0; i < 8; ++i) lo[i] = f2bf(lds[ci0 + i][x]);
  #pragma unroll
  for (int i = 0; i < 8; ++i) hi[i] = f2bf(lds[ci0 + 8 + i][x]);
  char* dbase = (char*)(g0 + (size_t)(b * 64 + y) * 4096);
  const int o = x * 128 + ci0 * 2, sw = (x & 7) << 4;
  *(us8*)(dbase + (o ^ sw)) = lo;
  *(us8*)(dbase + ((o + 16) ^ sw)) = hi;
}

// ---------------- the conv step kernel -------------------------------------------------
// WHICH=0: u = relu(g1*conv(grid,W1)+be1)            src=grid, dst=u
// WHICH=1: u2 = relu(g2*conv(u,W2)+be2); grid' = (1-bs)*grid + bs*u2; rgb out
// Block: 512 thr (8 waves) = one sample x 8 output rows x all 64 co x all 64 x.
// Stage 10 input rows (80KB) + all 9 tap weight tiles (72KB) = 152KB LDS, ONE
// barrier, then a barrier-free 9-tap MFMA loop (each wave only reads LDS).
template<int WHICH>
__launch_bounds__(512, 2)
__global__ void conv_kernel(const unsigned short* __restrict__ Wall,
                            const unsigned short* __restrict__ src,
                            unsigned short* __restrict__ dst,
                            const unsigned short* __restrict__ gold,
                            const float* __restrict__ film,
                            const float* __restrict__ blendp,
                            float* __restrict__ out, int t) {
  __shared__ unsigned short in_lds[10 * 4096];      // rows y0-1..y0+8, [x][ci] swizzled
  __shared__ unsigned short w_lds[9 * 4096];        // [tap][co][ci] swizzled
  const int tid  = threadIdx.x;
  const int wid  = tid >> 6;                        // wave id -> output row
  const int lane = tid & 63;
  const int l15  = lane & 15;
  const int lhi  = lane >> 4;
  const int s    = blockIdx.x >> 3;
  const int y0   = (blockIdx.x & 7) * 8;

  const unsigned short* srcs = src + (size_t)s * 262144;
  const unsigned short* Wb   = Wall + (size_t)((s * 2 + WHICH) * 9) * 4096;

  // stage 10 input rows: 80 x 1KB wave-chunks (10 per wave)
  #pragma unroll
  for (int q = 0; q < 10; ++q) {
    const int c   = q * 8 + wid;
    const int row = c >> 3, part = c & 7;
    const int gy  = (y0 + row + 63) & 63;
    gl_lds16(srcs + gy * 4096 + part * 512 + lane * 8, &in_lds[row * 4096 + part * 512]);
  }
  // stage all 9 taps of weights: 72 x 1KB wave-chunks (9 per wave)
  #pragma unroll
  for (int q = 0; q < 9; ++q) {
    const int c = q * 8 + wid;
    gl_lds16(Wb + c * 512 + lane * 8, &w_lds[c * 512]);
  }
  asm volatile("s_waitcnt vmcnt(0)" ::: "memory");
  __syncthreads();

  f32x4 acc[4][4];
  #pragma unroll
  for (int m = 0; m < 4; ++m)
    #pragma unroll
    for (int n = 0; n < 4; ++n)
      #pragma unroll
      for (int j = 0; j < 4; ++j) acc[m][n][j] = 0.f;

  #pragma unroll
  for (int tap = 0; tap < 9; ++tap) {
    const int ky = tap / 3, kx = tap % 3;
    short8 af[4][2], bfr[4][2];
    #pragma unroll
    for (int m = 0; m < 4; ++m) {                   // A frags: W[co][ci]
      const int co = m * 16 + l15;
      #pragma unroll
      for (int kk = 0; kk < 2; ++kk) {
        const int off = tap * 8192 + ((co * 128 + kk * 64 + lhi * 16) ^ ((co & 7) << 4));
        af[m][kk] = *(const short8*)((const char*)w_lds + off);
      }
    }
    const int r = wid + ky;                         // input row in LDS (0..9)
    #pragma unroll
    for (int n = 0; n < 4; ++n) {                   // B frags: in[x][ci]
      const int xs = (n * 16 + l15 + kx + 63) & 63; // circular x shift
      #pragma unroll
      for (int kk = 0; kk < 2; ++kk) {
        const int off = r * 8192 + ((xs * 128 + kk * 64 + lhi * 16) ^ ((xs & 7) << 4));
        bfr[n][kk] = *(const short8*)((const char*)in_lds + off);
      }
    }
    #pragma unroll
    for (int kk = 0; kk < 2; ++kk)
      #pragma unroll
      for (int m = 0; m < 4; ++m)
        #pragma unroll
        for (int n = 0; n < 4; ++n)
          acc[m][n] = __builtin_amdgcn_mfma_f32_16x16x32_bf16(af[m][kk], bfr[n][kk], acc[m][n], 0, 0, 0);
  }

  // ---- epilogue: FiLM + relu (+ blend + rgb for WHICH=1) ----
  const int y = y0 + wid;
  const float* fg = film + WHICH * 2 * 2048;        // g  [32][64]
  const float* fb = fg + 2048;                      // be [32][64]
  float bs = 0.f, obs = 0.f;
  if (WHICH == 1) { bs = 1.f / (1.f + expf(-blendp[0])); obs = 1.f - bs; }
  unsigned short* drow = dst + (size_t)s * 262144 + y * 4096;
  const unsigned short* grow = (WHICH == 1) ? (gold + (size_t)s * 262144 + y * 4096) : (const unsigned short*)nullptr;

  #pragma unroll
  for (int m = 0; m < 4; ++m) {
    const int co0 = m * 16 + lhi * 4;               // C/D: row(co) = lhi*4 + reg (m89)
    const float4 g  = *(const float4*)&fg[s * 64 + co0];
    const float4 be = *(const float4*)&fb[s * 64 + co0];
    #pragma unroll
    for (int n = 0; n < 4; ++n) {
      const int x = n * 16 + l15;                   // C/D: col(x) = lane&15
      const int off = (x * 128 + co0 * 2) ^ ((x & 7) << 4);
      const f32x4 v = acc[m][n];
      const float u0 = fmaxf(g.x * v[0] + be.x, 0.f);
      const float u1 = fmaxf(g.y * v[1] + be.y, 0.f);
      const float u2 = fmaxf(g.z * v[2] + be.z, 0.f);
      const float u3 = fmaxf(g.w * v[3] + be.w, 0.f);
      if (WHICH == 0) {
        ushort4 pk; pk.x = f2bf(u0); pk.y = f2bf(u1); pk.z = f2bf(u2); pk.w = f2bf(u3);
        *(ushort4*)((char*)drow + off) = pk;
      } else {
        const ushort4 od = *(const ushort4*)((const char*)grow + off);
        const float g0 = obs * bf2f(od.x) + bs * u0;
        const float g1 = obs * bf2f(od.y) + bs * u1;
        const float g2 = obs * bf2f(od.z) + bs * u2;
        const float g3 = obs * bf2f(od.w) + bs * u3;
        ushort4 pk; pk.x = f2bf(g0); pk.y = f2bf(g1); pk.z = f2bf(g2); pk.w = f2bf(g3);
        *(ushort4*)((char*)drow + off) = pk;
        if (co0 == 0) {                             // rgb channels 0..2
          const float r0 = 1.f / (1.f + expf(-g0));
          const float r1 = 1.f / (1.f + expf(-g1));
          const float r2 = 1.f / (1.f + expf(-g2));
          float* ob = out + 393216 + (size_t)((t * 32 + s) * 3) * 4096 + y * 64 + x;
          ob[0] = r0; ob[4096] = r1; ob[8192] = r2;
          if (t == 31) {                            // traj[-1] head copy
            float* o2 = out + (size_t)(s * 3) * 4096 + y * 64 + x;
            o2[0] = r0; o2[4096] = r1; o2[8192] = r2;
          }
        }
      }
    }
  }
}

extern "C" void kernel_launch(void* const* d_in, const int* in_sizes, int n_in,
                              void* d_out, int out_size, void* d_ws, size_t ws_size,
                              hipStream_t stream) {
  (void)in_sizes; (void)n_in; (void)out_size; (void)ws_size;
  const int*   labels = (const int*)d_in[0];
  const float* gin    = (const float*)d_in[1];
  const float* emb    = (const float*)d_in[2];
  const float* hw1    = (const float*)d_in[3];
  const float* hb1    = (const float*)d_in[4];
  const float* hw2    = (const float*)d_in[5];
  const float* hb2    = (const float*)d_in[6];
  const float* hw3    = (const float*)d_in[7];
  const float* hb3    = (const float*)d_in[8];
  const float* f1w1   = (const float*)d_in[9];
  const float* f1b1   = (const float*)d_in[10];
  const float* f1w2   = (const float*)d_in[11];
  const float* f1b2   = (const float*)d_in[12];
  const float* f2w1   = (const float*)d_in[13];
  const float* f2b1   = (const float*)d_in[14];
  const float* f2w2   = (const float*)d_in[15];
  const float* f2b2   = (const float*)d_in[16];
  const float* blend  = (const float*)d_in[17];
  float* out = (float*)d_out;

  char* ws = (char*)d_ws;                               // ~55.1 MB used
  unsigned short* grid0 = (unsigned short*)(ws + (size_t)0);         // 16 MB
  unsigned short* grid1 = (unsigned short*)(ws + (size_t)16777216);  // 16 MB
  unsigned short* ubuf  = (unsigned short*)(ws + (size_t)33554432);  // 16 MB
  unsigned short* Wbuf  = (unsigned short*)(ws + (size_t)50331648);  // 4.72 MB
  float* h2T  = (float*)(ws + (size_t)55050240);                     // 32 KB
  float* film = (float*)(ws + (size_t)55083008);                     // 32 KB

  hyper_kernel<<<32, 256, 0, stream>>>(labels, emb, hw1, hb1, hw2, hb2, h2T);
  film_kernel<<<dim3(32, 2), 128, 0, stream>>>(labels, emb, f1w1, f1b1, f1w2, f1b2,
                                               f2w1, f2b1, f2w2, f2b2, film);
  wgen_kernel<<<1152, 256, 0, stream>>>(h2T, hw3, hb3, Wbuf);
  init_kernel<<<2048, 256, 0, stream>>>(gin, grid0);

  for (int t = 0; t < 32; ++t) {
    unsigned short* gi = (t & 1) ? grid1 : grid0;
    unsigned short* go = (t & 1) ? grid0 : grid1;
    conv_kernel<0><<<256, 512, 0, stream>>>(Wbuf, gi, ubuf, nullptr, film, nullptr, nullptr, t);
    conv_kernel<1><<<256, 512, 0, stream>>>(Wbuf, ubuf, go, gi, film, blend, out, t);
  }
}

// Round 4
// 1224.254 us; speedup vs baseline: 1.1680x; 1.1680x over previous
//
#include <hip/hip_runtime.h>

// NCA with hypernetwork, MI355X bf16-MFMA implementation (round 3, resubmit —
// round 3 bench failed on GPU acquisition, never measured).
//
// Layouts (all in d_ws, rebuilt every call since ws is poisoned):
//   grid0/grid1/u : bf16, channels-last [s][y][x][ci], per-(y,x) 128B "ci-line",
//                   byte-swizzled  byte ^= ((x&7)<<4)   (bank-conflict-free ds_read_b128)
//   Wbuf          : bf16, [s][conv][tap][co][ci], per-co 128B ci-line,
//                   byte-swizzled  byte ^= ((co&7)<<4)
//
// Round-3 changes:
//   * wgen: register-double-buffered 8-group load pipeline (99us was one full
//     memory latency per 4-iter group: no MLP). 576 blocks, float2/lane.
//   * conv: XCD-binding block swizzle — all 8 row-blocks of sample s land on
//     XCD s%8 in BOTH conv dispatches, so sample state stays in that XCD's L2
//     across all 64 dispatches (W 576KB/XCD hot; active set ~2.5MB vs 4MB L2).

typedef __attribute__((ext_vector_type(8))) short short8;     // 8 bf16 = 4 VGPR (MFMA frag)
typedef __attribute__((ext_vector_type(4))) float f32x4;      // MFMA acc frag
typedef __attribute__((ext_vector_type(8))) unsigned short us8;

__device__ __forceinline__ unsigned short f2bf(float f) {     // RNE f32->bf16
  unsigned int u = __builtin_bit_cast(unsigned int, f);
  u = (u + 0x7FFFu + ((u >> 16) & 1u)) >> 16;
  return (unsigned short)u;
}
__device__ __forceinline__ float bf2f(unsigned short h) {
  unsigned int u = ((unsigned int)h) << 16;
  return __builtin_bit_cast(float, u);
}

__device__ __forceinline__ void gl_lds16(const void* g, void* l) {
  // 16B-wide async global->LDS; LDS dest is wave-uniform base + lane*16 (m104).
  __builtin_amdgcn_global_load_lds((const __attribute__((address_space(1))) void*)g,
                                   (__attribute__((address_space(3))) void*)l, 16, 0, 0);
}

// ---------------- hypernet trunk: cond -> h1 -> h2 (store h2 transposed [k][s]) --------
__global__ void hyper_kernel(const int* __restrict__ labels, const float* __restrict__ emb,
                             const float* __restrict__ hw1, const float* __restrict__ hb1,
                             const float* __restrict__ hw2, const float* __restrict__ hb2,
                             float* __restrict__ h2T) {
  __shared__ float cond[128];
  __shared__ float h1[256];
  const int s = blockIdx.x, j = threadIdx.x;        // 32 blocks x 256 threads
  if (j < 128) cond[j] = emb[(size_t)labels[s] * 128 + j];
  __syncthreads();
  float a = hb1[j];
  for (int k = 0; k < 128; ++k) a += cond[k] * hw1[k * 256 + j];
  h1[j] = fmaxf(a, 0.f);
  __syncthreads();
  float a2 = hb2[j];
  for (int k = 0; k < 256; ++k) a2 += h1[k] * hw2[k * 256 + j];
  h2T[j * 32 + s] = fmaxf(a2, 0.f);                 // [256][32]
}

// ---------------- FiLM params: film[4][32][64] = g1,be1,g2,be2 -------------------------
__global__ void film_kernel(const int* __restrict__ labels, const float* __restrict__ emb,
                            const float* __restrict__ f1w1, const float* __restrict__ f1b1,
                            const float* __restrict__ f1w2, const float* __restrict__ f1b2,
                            const float* __restrict__ f2w1, const float* __restrict__ f2b1,
                            const float* __restrict__ f2w2, const float* __restrict__ f2b2,
                            float* __restrict__ film) {
  __shared__ float cond[128];
  __shared__ float hid[128];
  const int s = blockIdx.x, which = blockIdx.y, j = threadIdx.x;   // (32,2) x 128
  const float* W1 = which ? f2w1 : f1w1;
  const float* B1 = which ? f2b1 : f1b1;
  const float* W2 = which ? f2w2 : f1w2;
  const float* B2 = which ? f2b2 : f1b2;
  cond[j] = emb[(size_t)labels[s] * 128 + j];
  __syncthreads();
  float a = B1[j];
  for (int k = 0; k < 128; ++k) a += cond[k] * W1[k * 128 + j];
  hid[j] = fmaxf(a, 0.f);
  __syncthreads();
  float p = B2[j];
  for (int k = 0; k < 128; ++k) p += hid[k] * W2[k * 128 + j];
  film[(size_t)((which * 2 + (j >> 6)) * 32 + s) * 64 + (j & 63)] = p;
}

// ---------------- weight generation: h2 @ hw3 + hb3, scatter to swizzled bf16 ----------
// 576 blocks x 256 threads. Thread = 2 cols (float2) x 8 samples (wave = sample
// group). Register double-buffer of 8 k-iterations: next group's 8 loads are
// issued BEFORE the current group's FMAs -> 8 x 512B in flight per wave, stalls
// overlap across the 9 waves/CU. hw3 read exactly once (75.5 MB).
__launch_bounds__(256)
__global__ void wgen_kernel(const float* __restrict__ h2T, const float* __restrict__ hw3,
                            const float* __restrict__ hb3, unsigned short* __restrict__ W) {
  __shared__ float h2l[8192];                       // [k=256][s=32]
  const int t = threadIdx.x;
  for (int i = t; i < 8192; i += 256) h2l[i] = h2T[i];
  __syncthreads();
  const int lane = t & 63, sg = t >> 6;
  const int j0 = blockIdx.x * 128 + lane * 2;
  const float* __restrict__ gp = hw3 + j0;
  const float* __restrict__ hp = h2l + sg * 8;

  float acc[16];                                    // [sample i][col c] = acc[i*2+c]
  #pragma unroll
  for (int i = 0; i < 16; ++i) acc[i] = 0.f;

  float2 bufA[8], bufB[8];
  #pragma unroll
  for (int u = 0; u < 8; ++u) bufA[u] = *(const float2*)(gp + (size_t)u * 73728);

  #pragma unroll 1
  for (int kc = 0; kc < 256; kc += 16) {
    // issue group B loads (k = kc+8..kc+15), then compute group A (k = kc..kc+7)
    #pragma unroll
    for (int u = 0; u < 8; ++u) bufB[u] = *(const float2*)(gp + (size_t)(kc + 8 + u) * 73728);
    #pragma unroll
    for (int u = 0; u < 8; ++u) {
      const float4 hA = *(const float4*)(hp + (kc + u) * 32);
      const float4 hB = *(const float4*)(hp + (kc + u) * 32 + 4);
      const float2 wv = bufA[u];
      acc[0]  += hA.x * wv.x; acc[1]  += hA.x * wv.y;
      acc[2]  += hA.y * wv.x; acc[3]  += hA.y * wv.y;
      acc[4]  += hA.z * wv.x; acc[5]  += hA.z * wv.y;
      acc[6]  += hA.w * wv.x; acc[7]  += hA.w * wv.y;
      acc[8]  += hB.x * wv.x; acc[9]  += hB.x * wv.y;
      acc[10] += hB.y * wv.x; acc[11] += hB.y * wv.y;
      acc[12] += hB.z * wv.x; acc[13] += hB.z * wv.y;
      acc[14] += hB.w * wv.x; acc[15] += hB.w * wv.y;
    }
    // issue group A' loads (k = kc+16..kc+23), then compute group B
    if (kc + 16 < 256) {
      #pragma unroll
      for (int u = 0; u < 8; ++u) bufA[u] = *(const float2*)(gp + (size_t)(kc + 16 + u) * 73728);
    }
    #pragma unroll
    for (int u = 0; u < 8; ++u) {
      const float4 hA = *(const float4*)(hp + (kc + 8 + u) * 32);
      const float4 hB = *(const float4*)(hp + (kc + 8 + u) * 32 + 4);
      const float2 wv = bufB[u];
      acc[0]  += hA.x * wv.x; acc[1]  += hA.x * wv.y;
      acc[2]  += hA.y * wv.x; acc[3]  += hA.y * wv.y;
      acc[4]  += hA.z * wv.x; acc[5]  += hA.z * wv.y;
      acc[6]  += hA.w * wv.x; acc[7]  += hA.w * wv.y;
      acc[8]  += hB.x * wv.x; acc[9]  += hB.x * wv.y;
      acc[10] += hB.y * wv.x; acc[11] += hB.y * wv.y;
      acc[12] += hB.z * wv.x; acc[13] += hB.z * wv.y;
      acc[14] += hB.w * wv.x; acc[15] += hB.w * wv.y;
    }
  }

  #pragma unroll
  for (int c = 0; c < 2; ++c) {
    const int j  = j0 + c;
    const float bias = hb3[j];
    const int cv = j / 36864;               // which conv
    const int r  = j - cv * 36864;
    const int co = r / 576;
    const int r2 = r - co * 576;
    const int ci = r2 / 9;
    const int tap = r2 - ci * 9;            // ky*3+kx
    const int sw = (co * 64 + ci) ^ ((co & 7) << 3);   // ushort-unit swizzle (byte<<4)
    #pragma unroll
    for (int i = 0; i < 8; ++i) {
      const int s2 = sg * 8 + i;
      W[(size_t)((s2 * 2 + cv) * 9 + tap) * 4096 + sw] = f2bf(acc[i * 2 + c] + bias);
    }
  }
}

// ---------------- initial grid: [B,C,H,W] f32 -> swizzled channels-last bf16 -----------
__global__ void init_kernel(const float* __restrict__ gin, unsigned short* __restrict__ g0) {
  __shared__ float lds[64][65];                     // +1 pad
  const int b = blockIdx.x >> 6, y = blockIdx.x & 63;   // 2048 blocks x 256 threads
  const int t = threadIdx.x;
  {
    const int ci = t >> 2, xq = t & 3;
    const float* base = gin + (size_t)((b * 64 + ci) * 64 + y) * 64;
    #pragma unroll
    for (int q = 0; q < 4; ++q) {
      const int x0 = (xq + q * 4) * 4;
      const float4 v = *(const float4*)(base + x0);
      lds[ci][x0+0] = v.x; lds[ci][x0+1] = v.y; lds[ci][x0+2] = v.z; lds[ci][x0+3] = v.w;
    }
  }
  __syncthreads();
  const int x = t >> 2, cq = t & 3, ci0 = cq * 16;
  us8 lo, hi;
  #pragma unroll
  for (int i = 0; i < 8; ++i) lo[i] = f2bf(lds[ci0 + i][x]);
  #pragma unroll
  for (int i = 0; i < 8; ++i) hi[i] = f2bf(lds[ci0 + 8 + i][x]);
  char* dbase = (char*)(g0 + (size_t)(b * 64 + y) * 4096);
  const int o = x * 128 + ci0 * 2, sw = (x & 7) << 4;
  *(us8*)(dbase + (o ^ sw)) = lo;
  *(us8*)(dbase + ((o + 16) ^ sw)) = hi;
}

// ---------------- the conv step kernel -------------------------------------------------
// WHICH=0: u = relu(g1*conv(grid,W1)+be1)            src=grid, dst=u
// WHICH=1: u2 = relu(g2*conv(u,W2)+be2); grid' = (1-bs)*grid + bs*u2; rgb out
// Block: 512 thr (8 waves) = one sample x 8 output rows x all 64 co x all 64 x.
// XCD-binding swizzle: blocks of sample s land on XCD s%8 (round-robin CP
// dispatch), keeping the sample's grid/u/W L2-resident across all dispatches.
template<int WHICH>
__launch_bounds__(512, 2)
__global__ void conv_kernel(const unsigned short* __restrict__ Wall,
                            const unsigned short* __restrict__ src,
                            unsigned short* __restrict__ dst,
                            const unsigned short* __restrict__ gold,
                            const float* __restrict__ film,
                            const float* __restrict__ blendp,
                            float* __restrict__ out, int t) {
  __shared__ unsigned short in_lds[10 * 4096];      // rows y0-1..y0+8, [x][ci] swizzled
  __shared__ unsigned short w_lds[9 * 4096];        // [tap][co][ci] swizzled
  const int tid  = threadIdx.x;
  const int wid  = tid >> 6;                        // wave id -> output row
  const int lane = tid & 63;
  const int l15  = lane & 15;
  const int lhi  = lane >> 4;
  const int b    = blockIdx.x;
  const int s    = (b & 7) + 8 * ((b >> 3) & 3);    // sample -> XCD b&7 == s%8
  const int y0   = (b >> 5) * 8;

  const unsigned short* srcs = src + (size_t)s * 262144;
  const unsigned short* Wb   = Wall + (size_t)((s * 2 + WHICH) * 9) * 4096;

  // stage 10 input rows: 80 x 1KB wave-chunks (10 per wave)
  #pragma unroll
  for (int q = 0; q < 10; ++q) {
    const int c   = q * 8 + wid;
    const int row = c >> 3, part = c & 7;
    const int gy  = (y0 + row + 63) & 63;
    gl_lds16(srcs + gy * 4096 + part * 512 + lane * 8, &in_lds[row * 4096 + part * 512]);
  }
  // stage all 9 taps of weights: 72 x 1KB wave-chunks (9 per wave)
  #pragma unroll
  for (int q = 0; q < 9; ++q) {
    const int c = q * 8 + wid;
    gl_lds16(Wb + c * 512 + lane * 8, &w_lds[c * 512]);
  }
  asm volatile("s_waitcnt vmcnt(0)" ::: "memory");
  __syncthreads();

  f32x4 acc[4][4];
  #pragma unroll
  for (int m = 0; m < 4; ++m)
    #pragma unroll
    for (int n = 0; n < 4; ++n)
      #pragma unroll
      for (int j = 0; j < 4; ++j) acc[m][n][j] = 0.f;

  #pragma unroll
  for (int tap = 0; tap < 9; ++tap) {
    const int ky = tap / 3, kx = tap % 3;
    short8 af[4][2], bfr[4][2];
    #pragma unroll
    for (int m = 0; m < 4; ++m) {                   // A frags: W[co][ci]
      const int co = m * 16 + l15;
      #pragma unroll
      for (int kk = 0; kk < 2; ++kk) {
        const int off = tap * 8192 + ((co * 128 + kk * 64 + lhi * 16) ^ ((co & 7) << 4));
        af[m][kk] = *(const short8*)((const char*)w_lds + off);
      }
    }
    const int r = wid + ky;                         // input row in LDS (0..9)
    #pragma unroll
    for (int n = 0; n < 4; ++n) {                   // B frags: in[x][ci]
      const int xs = (n * 16 + l15 + kx + 63) & 63; // circular x shift
      #pragma unroll
      for (int kk = 0; kk < 2; ++kk) {
        const int off = r * 8192 + ((xs * 128 + kk * 64 + lhi * 16) ^ ((xs & 7) << 4));
        bfr[n][kk] = *(const short8*)((const char*)in_lds + off);
      }
    }
    #pragma unroll
    for (int kk = 0; kk < 2; ++kk)
      #pragma unroll
      for (int m = 0; m < 4; ++m)
        #pragma unroll
        for (int n = 0; n < 4; ++n)
          acc[m][n] = __builtin_amdgcn_mfma_f32_16x16x32_bf16(af[m][kk], bfr[n][kk], acc[m][n], 0, 0, 0);
  }

  // ---- epilogue: FiLM + relu (+ blend + rgb for WHICH=1) ----
  const int y = y0 + wid;
  const float* fg = film + WHICH * 2 * 2048;        // g  [32][64]
  const float* fb = fg + 2048;                      // be [32][64]
  float bs = 0.f, obs = 0.f;
  if (WHICH == 1) { bs = 1.f / (1.f + expf(-blendp[0])); obs = 1.f - bs; }
  unsigned short* drow = dst + (size_t)s * 262144 + y * 4096;
  const unsigned short* grow = (WHICH == 1) ? (gold + (size_t)s * 262144 + y * 4096) : (const unsigned short*)nullptr;

  #pragma unroll
  for (int m = 0; m < 4; ++m) {
    const int co0 = m * 16 + lhi * 4;               // C/D: row(co) = lhi*4 + reg (m89)
    const float4 g  = *(const float4*)&fg[s * 64 + co0];
    const float4 be = *(const float4*)&fb[s * 64 + co0];
    #pragma unroll
    for (int n = 0; n < 4; ++n) {
      const int x = n * 16 + l15;                   // C/D: col(x) = lane&15
      const int off = (x * 128 + co0 * 2) ^ ((x & 7) << 4);
      const f32x4 v = acc[m][n];
      const float u0 = fmaxf(g.x * v[0] + be.x, 0.f);
      const float u1 = fmaxf(g.y * v[1] + be.y, 0.f);
      const float u2 = fmaxf(g.z * v[2] + be.z, 0.f);
      const float u3 = fmaxf(g.w * v[3] + be.w, 0.f);
      if (WHICH == 0) {
        ushort4 pk; pk.x = f2bf(u0); pk.y = f2bf(u1); pk.z = f2bf(u2); pk.w = f2bf(u3);
        *(ushort4*)((char*)drow + off) = pk;
      } else {
        const ushort4 od = *(const ushort4*)((const char*)grow + off);
        const float g0 = obs * bf2f(od.x) + bs * u0;
        const float g1 = obs * bf2f(od.y) + bs * u1;
        const float g2 = obs * bf2f(od.z) + bs * u2;
        const float g3 = obs * bf2f(od.w) + bs * u3;
        ushort4 pk; pk.x = f2bf(g0); pk.y = f2bf(g1); pk.z = f2bf(g2); pk.w = f2bf(g3);
        *(ushort4*)((char*)drow + off) = pk;
        if (co0 == 0) {                             // rgb channels 0..2
          const float r0 = 1.f / (1.f + expf(-g0));
          const float r1 = 1.f / (1.f + expf(-g1));
          const float r2 = 1.f / (1.f + expf(-g2));
          float* ob = out + 393216 + (size_t)((t * 32 + s) * 3) * 4096 + y * 64 + x;
          ob[0] = r0; ob[4096] = r1; ob[8192] = r2;
          if (t == 31) {                            // traj[-1] head copy
            float* o2 = out + (size_t)(s * 3) * 4096 + y * 64 + x;
            o2[0] = r0; o2[4096] = r1; o2[8192] = r2;
          }
        }
      }
    }
  }
}

extern "C" void kernel_launch(void* const* d_in, const int* in_sizes, int n_in,
                              void* d_out, int out_size, void* d_ws, size_t ws_size,
                              hipStream_t stream) {
  (void)in_sizes; (void)n_in; (void)out_size; (void)ws_size;
  const int*   labels = (const int*)d_in[0];
  const float* gin    = (const float*)d_in[1];
  const float* emb    = (const float*)d_in[2];
  const float* hw1    = (const float*)d_in[3];
  const float* hb1    = (const float*)d_in[4];
  const float* hw2    = (const float*)d_in[5];
  const float* hb2    = (const float*)d_in[6];
  const float* hw3    = (const float*)d_in[7];
  const float* hb3    = (const float*)d_in[8];
  const float* f1w1   = (const float*)d_in[9];
  const float* f1b1   = (const float*)d_in[10];
  const float* f1w2   = (const float*)d_in[11];
  const float* f1b2   = (const float*)d_in[12];
  const float* f2w1   = (const float*)d_in[13];
  const float* f2b1   = (const float*)d_in[14];
  const float* f2w2   = (const float*)d_in[15];
  const float* f2b2   = (const float*)d_in[16];
  const float* blend  = (const float*)d_in[17];
  float* out = (float*)d_out;

  char* ws = (char*)d_ws;                               // ~55.1 MB used
  unsigned short* grid0 = (unsigned short*)(ws + (size_t)0);         // 16 MB
  unsigned short* grid1 = (unsigned short*)(ws + (size_t)16777216);  // 16 MB
  unsigned short* ubuf  = (unsigned short*)(ws + (size_t)33554432);  // 16 MB
  unsigned short* Wbuf  = (unsigned short*)(ws + (size_t)50331648);  // 4.72 MB
  float* h2T  = (float*)(ws + (size_t)55050240);                     // 32 KB
  float* film = (float*)(ws + (size_t)55083008);                     // 32 KB

  hyper_kernel<<<32, 256, 0, stream>>>(labels, emb, hw1, hb1, hw2, hb2, h2T);
  film_kernel<<<dim3(32, 2), 128, 0, stream>>>(labels, emb, f1w1, f1b1, f1w2, f1b2,
                                               f2w1, f2b1, f2w2, f2b2, film);
  wgen_kernel<<<576, 256, 0, stream>>>(h2T, hw3, hb3, Wbuf);
  init_kernel<<<2048, 256, 0, stream>>>(gin, grid0);

  for (int t = 0; t < 32; ++t) {
    unsigned short* gi = (t & 1) ? grid1 : grid0;
    unsigned short* go = (t & 1) ? grid0 : grid1;
    conv_kernel<0><<<256, 512, 0, stream>>>(Wbuf, gi, ubuf, nullptr, film, nullptr, nullptr, t);
    conv_kernel<1><<<256, 512, 0, stream>>>(Wbuf, ubuf, go, gi, film, blend, out, t);
  }
}